// Round 4
// baseline (532.006 us; speedup 1.0000x reference)
//
#include <hip/hip_runtime.h>
#include <hip/hip_bf16.h>

// SparseConv2D: 32x112x112x128 fp32 NHWC, 3x3 SAME, 126 out ch x 5 taps.
// Implicit GEMM on bf16 MFMA, dense-9-tap.
// R4: block = (image, row-pair). 4 waves = 2 rows x 2 N-halves; each wave owns
// 7 m-tiles x 64 N-cols (4 n-frags) so every a-frag LDS read feeds 4 MFMAs
// (halves LDS-pipe time vs R3). A staged fp32->bf16 into double-buffered LDS,
// two 16-ch halves pipelined inside the tap loop; 1 barrier/phase.
// B fragments in registers from L2-hot Bws, prefetched one tap ahead.

typedef __attribute__((ext_vector_type(8))) __bf16 bf16x8;
typedef __attribute__((ext_vector_type(4))) float f32x4;

__device__ __forceinline__ unsigned short f2bf(float f) {
  unsigned int u = __builtin_bit_cast(unsigned int, f);
  u += 0x7fffu + ((u >> 16) & 1u);   // RNE (inputs are finite normals)
  return (unsigned short)(u >> 16);
}

// Bws[p][cc][n][c] bf16: dense kernel, n in [0,128) (126..127 zero), c in [0,32)
__global__ __launch_bounds__(256) void build_B(const float* __restrict__ sk,
                                               const int* __restrict__ patterns,
                                               unsigned short* __restrict__ Bws) {
  int idx = blockIdx.x * 256 + threadIdx.x;
  if (idx >= 9 * 128 * 128) return;
  int c = idx & 127;
  int n = (idx >> 7) & 127;
  int p = idx >> 14;
  float v = 0.f;
  if (n < 126) {
#pragma unroll
    for (int j = 0; j < 5; ++j)
      if (patterns[n * 5 + j] == p) v = sk[(j * 128 + c) * 126 + n];
  }
  int cc = c >> 5, cl = c & 31;
  Bws[(((p * 4 + cc) * 128) + n) * 32 + cl] = f2bf(v);
}

__global__ __launch_bounds__(256, 2) void conv_main(const float* __restrict__ in,
                                                    const unsigned short* __restrict__ Bws,
                                                    const float* __restrict__ bias,
                                                    float* __restrict__ out) {
  // A: 4 halo rows x 114 px x 32 ch (padded ->40), double-buffered: 72,960 B
  __shared__ unsigned short Alds[2][4 * 114 * 40];

  const int tid = threadIdx.x;
  const int bid = blockIdx.x;
  const int nimg = bid / 56;
  const int y0 = (bid - nimg * 56) * 2;     // row pair y0, y0+1
  const int lane = tid & 63;
  const int w = tid >> 6;
  const int r = w >> 1;                     // output row within pair
  const int nh = w & 1;                     // N half: cols [64*nh, 64*nh+64)
  const int quad = lane >> 4;
  const int lrow = lane & 15;

  const float* inb = in + (size_t)nimg * 112 * 112 * 128;

  f32x4 acc[7][4];
#pragma unroll
  for (int mt = 0; mt < 7; ++mt)
#pragma unroll
    for (int jf = 0; jf < 4; ++jf) acc[mt][jf] = (f32x4)0.f;

  // A staging, one 16-ch half: 4 rows x 114 px x 4 float4 = 1824 pieces
  float4 pf[8];
  auto loadA = [&](int cc, int hh) {
#pragma unroll
    for (int it = 0; it < 8; ++it) {
      int i = tid + it * 256;
      float4 v = make_float4(0.f, 0.f, 0.f, 0.f);
      if (i < 1824) {
        int c4 = i & 3;
        int rest = i >> 2;
        int hr = rest / 114;
        int hx = rest - hr * 114;
        int gy = y0 + hr - 1;
        int gx = hx - 1;
        if ((unsigned)gy < 112u && (unsigned)gx < 112u)
          v = *(const float4*)(inb + ((size_t)gy * 112 + gx) * 128 + cc * 32 + hh * 16 + c4 * 4);
      }
      pf[it] = v;
    }
  };
  auto writeA = [&](int buf, int hh) {
#pragma unroll
    for (int it = 0; it < 8; ++it) {
      int i = tid + it * 256;
      if (i < 1824) {
        int c4 = i & 3;
        int rest = i >> 2;
        int hr = rest / 114;
        int hx = rest - hr * 114;
        ushort4 s;
        s.x = f2bf(pf[it].x); s.y = f2bf(pf[it].y);
        s.z = f2bf(pf[it].z); s.w = f2bf(pf[it].w);
        *(ushort4*)&Alds[buf][(hr * 114 + hx) * 40 + hh * 16 + c4 * 4] = s;
      }
    }
  };

  auto bload = [&](int cc, int p, bf16x8* b) {
#pragma unroll
    for (int jf = 0; jf < 4; ++jf)
      b[jf] = *(const bf16x8*)(Bws +
          (((size_t)(p * 4 + cc) * 128 + nh * 64 + jf * 16 + lrow) * 32 + quad * 8));
  };

  // prologue: stage phase 0 into buf 0
  loadA(0, 0); writeA(0, 0);
  loadA(0, 1); writeA(0, 1);
  __syncthreads();

#pragma unroll 1
  for (int cc = 0; cc < 4; ++cc) {
    const int buf = cc & 1;
    bf16x8 bcur[4], bnxt[4];
    bload(cc, 0, bcur);
    if (cc < 3) loadA(cc + 1, 0);     // HBM loads in flight over taps 0..4

#pragma unroll
    for (int p = 0; p < 9; ++p) {
      if (p < 8) bload(cc, p + 1, bnxt);
      const int dy = p / 3;           // halo row offset
      const int px = p - dy * 3;      // x shift
      const int abase = ((r + dy) * 114 + px + lrow) * 40 + quad * 8;
#pragma unroll
      for (int mt = 0; mt < 7; ++mt) {
        bf16x8 a = *(const bf16x8*)&Alds[buf][abase + mt * 16 * 40];
        acc[mt][0] = __builtin_amdgcn_mfma_f32_16x16x32_bf16(a, bcur[0], acc[mt][0], 0, 0, 0);
        acc[mt][1] = __builtin_amdgcn_mfma_f32_16x16x32_bf16(a, bcur[1], acc[mt][1], 0, 0, 0);
        acc[mt][2] = __builtin_amdgcn_mfma_f32_16x16x32_bf16(a, bcur[2], acc[mt][2], 0, 0, 0);
        acc[mt][3] = __builtin_amdgcn_mfma_f32_16x16x32_bf16(a, bcur[3], acc[mt][3], 0, 0, 0);
      }
      if (p < 8) {
#pragma unroll
        for (int jf = 0; jf < 4; ++jf) bcur[jf] = bnxt[jf];
      }
      if (cc < 3 && p == 4) {
        writeA(buf ^ 1, 0);           // h0 loads covered by taps 0..4
        loadA(cc + 1, 1);             // h1 loads covered by taps 5..8
      }
    }
    if (cc < 3) writeA(buf ^ 1, 1);
    __syncthreads();                  // buf^1 ready; all reads of buf done
  }

  // epilogue: C/D layout col = lane&15 (N), row = quad*4 + reg (M)
  float* outrow = out + ((size_t)(nimg * 112 + y0 + r)) * 112 * 126;
#pragma unroll
  for (int jf = 0; jf < 4; ++jf) {
    const int k = nh * 64 + jf * 16 + lrow;
    if (k < 126) {
      const float bv = bias[k];
#pragma unroll
      for (int mt = 0; mt < 7; ++mt) {
#pragma unroll
        for (int rg = 0; rg < 4; ++rg) {
          int x = mt * 16 + quad * 4 + rg;
          float v = acc[mt][jf][rg] + bv;
          outrow[(size_t)x * 126 + k] = v > 0.f ? v : 0.f;
        }
      }
    }
  }
}

extern "C" void kernel_launch(void* const* d_in, const int* in_sizes, int n_in,
                              void* d_out, int out_size, void* d_ws, size_t ws_size,
                              hipStream_t stream) {
  const float* in = (const float*)d_in[0];        // (32,112,112,128) fp32
  const float* sk = (const float*)d_in[1];        // (5,128,126) fp32
  const float* bias = (const float*)d_in[2];      // (126,) fp32
  const int* patterns = (const int*)d_in[3];      // (126,5) int32
  float* out = (float*)d_out;                     // (32,112,112,126) fp32
  unsigned short* Bws = (unsigned short*)d_ws;    // 9*4*128*32 bf16 = 294,912 B

  build_B<<<dim3(576), dim3(256), 0, stream>>>(sk, patterns, Bws);
  conv_main<<<dim3(32 * 56), dim3(256), 0, stream>>>(in, Bws, bias, out);
}